// Round 10
// baseline (85.411 us; speedup 1.0000x reference)
//
#include <hip/hip_runtime.h>
#include <cstdint>

// ---- problem dims ----
constexpr int NB = 512, NTAU = 4, ND = 5, NDX = 256, NDZ = 16, NH = 64;
constexpr int NM  = ND * NDZ;          // 80
constexpr int NTM = NTAU * NM;         // 320
constexpr int NSAMP = NB * NTAU + NB;  // 2560 (past samples then t samples)
constexpr float LOG2PI_F = 1.8378770664093453f;

typedef __attribute__((ext_vector_type(8))) short bf16x8;
typedef __attribute__((ext_vector_type(4))) float f32x4;

// ---- counter-based RNG (distribution-exact stand-in for jax.random) ----
__device__ __forceinline__ unsigned long long mix64(unsigned long long z) {
  z += 0x9E3779B97F4A7C15ull;
  z = (z ^ (z >> 30)) * 0xBF58476D1CE4E5B9ull;
  z = (z ^ (z >> 27)) * 0x94D049BB133111EBull;
  return z ^ (z >> 31);
}
__device__ __forceinline__ float u01f(unsigned long long h) {
  return ((float)(unsigned)(h >> 40) + 0.5f) * (1.0f / 16777216.0f);
}
__device__ __forceinline__ float rng_normal(unsigned long long salt, unsigned long long idx) {
  float u1 = u01f(mix64(salt + 2ull * idx));
  float u2 = u01f(mix64(salt + 2ull * idx + 1ull));
  float r = sqrtf(-2.0f * logf(u1));
  return r * cosf(6.283185307179586f * u2);
}
constexpr unsigned long long SALT_ADJ = 0x1000000000000ull;
constexpr unsigned long long SALT_EP  = 0x2000000000000ull;
constexpr unsigned long long SALT_ET  = 0x3000000000000ull;

__device__ __forceinline__ short f2bf(float f) {
  unsigned u = __float_as_uint(f);
  unsigned r = (u + 0x7FFFu + ((u >> 16) & 1u)) >> 16;
  return (short)r;
}

// =====================================================================
// K1: encoder GEMM (inline B from w_enc*eW0) + fused reparameterization,
//     PLUS independent prep block-ranges (co-scheduled, consumed by K2):
// [0,400)    enc: d=bid/80, zq=(bid%80)/20, sb=bid%20
// [400,560)  QtD prep (decoder weights, K=32 padded bf16)
// [560,960)  TtB prep (transition weights transposed bf16)
// [960,1280) yT prep (y transposed for dec recon reads)
// =====================================================================
__global__ __launch_bounds__(512) void k_enc_mfma(
    const float* __restrict__ x, const float* __restrict__ y,
    const float* __restrict__ w_enc, const float* __restrict__ eW0,
    const float* __restrict__ b0, const float* __restrict__ W1,
    const float* __restrict__ b1, const float* __restrict__ lve,
    float* __restrict__ z_past, float* __restrict__ mu_t, float* __restrict__ z_t,
    const float* __restrict__ w_dec, const float* __restrict__ dW0,
    short* __restrict__ QtD,
    const float* __restrict__ tW0, short* __restrict__ TtB,
    float* __restrict__ yT)
{
  __shared__ __align__(16) char smem[40448];
  const int bid = blockIdx.x;
  const int tid = threadIdx.x;

  if (bid < 400) {
    short* Bs     = (short*)smem;                    // 64*264 shorts
    float* wenc_s = (float*)(smem + 33792);          // 4*256 floats
    float (*mu_s)[4] = (float(*)[4])(smem + 37888);  // [128][4]

    const int d = bid / 80;
    const int r80 = bid % 80;
    const int zq = r80 / 20;
    const int s0 = (r80 % 20) * 128;
    const int w = tid >> 6, l = tid & 63;
    const int lrow = l & 15, g = l >> 4;

    // stage w_enc rows for the block's 4 z values
    for (int i = tid; i < 4 * NDX; i += 512) {
      int zi = i >> 8, k = i & 255;
      wenc_s[i] = w_enc[((size_t)d * NDZ + zq * 4 + zi) * NDX + k];
    }

    // A fragments: f32 direct read + inline f2bf (bit-identical to bf16 path)
    const int srow = s0 + w * 16 + lrow;
    const float* Asrc = (srow < NB * NTAU)
        ? &x[((size_t)srow * ND + d) * NDX]
        : &y[((size_t)(srow - NB * NTAU) * ND + d) * NDX];
    bf16x8 a[8];
    #pragma unroll
    for (int ks = 0; ks < 8; ++ks) {
      const float* p = Asrc + g * 8 + ks * 32;
      float4 f0 = *(const float4*)p;
      float4 f1 = *(const float4*)(p + 4);
      a[ks][0] = f2bf(f0.x); a[ks][1] = f2bf(f0.y);
      a[ks][2] = f2bf(f0.z); a[ks][3] = f2bf(f0.w);
      a[ks][4] = f2bf(f1.x); a[ks][5] = f2bf(f1.y);
      a[ks][6] = f2bf(f1.z); a[ks][7] = f2bf(f1.w);
    }
    __syncthreads();

    const int c  = tid >> 3;         // 0..63 (output col within z-group)
    const int kc = (tid & 7) * 32;   // K chunk

    for (int zi = 0; zi < 4; ++zi) {
      const int z = zq * 4 + zi;
      // inline B staging: Bs[c*264+k] = f2bf(w_enc[d,z,k] * eW0[z,k,c])
      {
        const float* ep = eW0 + ((size_t)z * NDX + kc) * NH + c;
        short* dst = Bs + c * 264 + kc;
        #pragma unroll
        for (int jb = 0; jb < 4; ++jb) {
          bf16x8 o;
          #pragma unroll
          for (int j = 0; j < 8; ++j) {
            float v = wenc_s[zi * 256 + kc + jb * 8 + j] * ep[(jb * 8 + j) * NH];
            o[j] = f2bf(v);
          }
          *(bf16x8*)(dst + jb * 8) = o;
        }
      }
      __syncthreads();

      f32x4 acc[4] = {};
      #pragma unroll
      for (int nt = 0; nt < 4; ++nt) {
        const short* Brow = Bs + (nt * 16 + lrow) * 264 + g * 8;
        #pragma unroll
        for (int ks = 0; ks < 8; ++ks) {
          bf16x8 bv = *(const bf16x8*)(Brow + ks * 32);
          acc[nt] = __builtin_amdgcn_mfma_f32_16x16x32_bf16(a[ks], bv, acc[nt], 0, 0, 0);
        }
      }

      float b0v[4], w1v[4];
      #pragma unroll
      for (int nt = 0; nt < 4; ++nt) {
        int h = nt * 16 + lrow;
        b0v[nt] = b0[z * NH + h];
        w1v[nt] = W1[z * NH + h];
      }
      const float b1v = b1[z];
      #pragma unroll
      for (int reg = 0; reg < 4; ++reg) {
        float v = 0.0f;
        #pragma unroll
        for (int nt = 0; nt < 4; ++nt) {
          float hv = acc[nt][reg] + b0v[nt];
          hv = fmaxf(hv, 0.01f * hv);
          v += hv * w1v[nt];
        }
        #pragma unroll
        for (int off = 1; off < 16; off <<= 1) v += __shfl_xor(v, off, 16);
        if (lrow == 0)
          mu_s[w * 16 + g * 4 + reg][zi] = v + b1v;
      }
      __syncthreads();
    }

    // fused reparameterization: 512 threads x 1 element (sl, zi)
    {
      const int sl = tid >> 2, zi = tid & 3;
      const int z = zq * 4 + zi;
      const int s = s0 + sl;
      const int m = d * NDZ + z;
      float mu = mu_s[sl][zi];
      float qs = expf(0.5f * lve[d]);
      if (s < NB * NTAU) {
        float eps = rng_normal(SALT_EP, (unsigned long long)s * NM + m);
        z_past[(size_t)s * NM + m] = mu + qs * eps;
      } else {
        int b = s - NB * NTAU;
        float eps = rng_normal(SALT_ET, (unsigned long long)b * NM + m);
        size_t o = (size_t)b * NM + m;
        mu_t[o] = mu;
        z_t[o]  = mu + qs * eps;
      }
    }
  } else if (bid < 560) {
    // QtD[((d*256+xx)*64+h)][k<32] = bf16(w_dec[d,xx,z]*dW0[xx,z,h]), 0-pad
    int t = (bid - 400) * 512 + tid;     // < 81920
    int d = t / (NDX * NH);
    int r = t % (NDX * NH);
    int xx = r >> 6, h = r & 63;
    size_t base = (size_t)t * 32;
    #pragma unroll
    for (int z = 0; z < NDZ; ++z)
      QtD[base + z] = f2bf(w_dec[((size_t)d * NDX + xx) * NDZ + z] *
                           dW0[((size_t)xx * NDZ + z) * NH + h]);
    #pragma unroll
    for (int z = NDZ; z < 32; ++z) QtD[base + z] = 0;
  } else if (bid < 960) {
    // TtB[m][h][k] = bf16(tW0[m][k][h]) via LDS transpose
    short (*lds)[65] = (short(*)[65])smem;
    int r = bid - 560;
    int kt = r % 5, m = r / 5;
    int k0 = kt * 64;
    for (int idx = tid; idx < 64 * 64; idx += 512) {
      int hh = idx & 63, kk = idx >> 6;
      lds[kk][hh] = f2bf(tW0[((size_t)m * NTM + k0 + kk) * NH + hh]);
    }
    __syncthreads();
    for (int idx = tid; idx < 64 * 64; idx += 512) {
      int kk = idx & 63, hh = idx >> 6;
      TtB[((size_t)m * NH + hh) * NTM + k0 + kk] = lds[kk][hh];
    }
  } else {
    // yT[d][xx][b] = y[b][d][xx], 4 b's per thread
    int e0 = ((bid - 960) * 512 + tid) * 4;   // < 655360
    int d = e0 / (NDX * NB);
    int rem = e0 % (NDX * NB);
    int xx = rem >> 9, b0i = rem & 511;
    float4 o;
    o.x = y[((size_t)(b0i + 0) * ND + d) * NDX + xx];
    o.y = y[((size_t)(b0i + 1) * ND + d) * NDX + xx];
    o.z = y[((size_t)(b0i + 2) * ND + d) * NDX + xx];
    o.w = y[((size_t)(b0i + 3) * ND + d) * NDX + xx];
    *(float4*)&yT[e0] = o;
  }
}

// =====================================================================
// K2: blocks [0,320) = transition GEMM + KL (register-direct gating,
//     inline em=expf(-mask)); blocks [320,1600) = decoder + recon.
// =====================================================================
__global__ __launch_bounds__(512) void k_tail(
    const float* __restrict__ mask_param, const float* __restrict__ z_past,
    const short* __restrict__ TtB,
    const float* __restrict__ tb0, const float* __restrict__ tW1,
    const float* __restrict__ tb1, const float* __restrict__ lve,
    const float* __restrict__ t_logvar, const float* __restrict__ mu_t,
    float* __restrict__ kl_partial,
    const float* __restrict__ zt, const short* __restrict__ QtD,
    const float* __restrict__ yT, const float* __restrict__ db0,
    const float* __restrict__ dW1, const float* __restrict__ db1,
    const float* __restrict__ lvd, float* __restrict__ rec_partial)
{
  __shared__ __align__(16) short Bls[64 * 328];
  __shared__ float ems[NTM];
  __shared__ float redb[8];

  const int bid = blockIdx.x;
  const int tid = threadIdx.x;

  if (bid < 320) {
    // ---------------- transition + KL ----------------
    const int m = bid >> 2;
    const int b0 = (bid & 3) * 128;
    const int w = tid >> 6, l = tid & 63;
    const int lrow = l & 15, g = l >> 4;

    for (int i = tid; i < NTM; i += 512) {
      int t = i / NM, s = i - t * NM;
      ems[i] = expf(-mask_param[(t * NM + m) * NM + s]);
    }
    {
      const int r = tid >> 3;
      const int c0 = (tid & 7) * 40;
      const short* src = TtB + ((size_t)(m * NH + r)) * NTM + c0;
      short* dst = Bls + r * 328 + c0;
      #pragma unroll
      for (int j = 0; j < 5; ++j)
        *(bf16x8*)(dst + j * 8) = *(const bf16x8*)(src + j * 8);
    }
    __syncthreads();

    const int brow = b0 + w * 16 + lrow;
    const float* zrow = z_past + (size_t)brow * NTM;
    bf16x8 a[10];
    #pragma unroll
    for (int ks = 0; ks < 10; ++ks) {
      const int tm0 = g * 8 + ks * 32;
      const int t = tm0 / NM;
      const int s0 = tm0 - t * NM;
      unsigned long long aibase =
          ((unsigned long long)((brow * NTAU + t) * NM + m)) * NM + s0;
      unsigned long long h0 = mix64(SALT_ADJ + aibase);
      unsigned long long h1 = mix64(SALT_ADJ + aibase + 2);
      unsigned long long h2 = mix64(SALT_ADJ + aibase + 4);
      unsigned long long h3 = mix64(SALT_ADJ + aibase + 6);
      float u[8];
      u[0] = ((float)(unsigned)(h0 >> 40) + 0.5f) * (1.0f / 16777216.0f);
      u[1] = ((float)((unsigned)(h0 >> 16) & 0xFFFFFFu) + 0.5f) * (1.0f / 16777216.0f);
      u[2] = ((float)(unsigned)(h1 >> 40) + 0.5f) * (1.0f / 16777216.0f);
      u[3] = ((float)((unsigned)(h1 >> 16) & 0xFFFFFFu) + 0.5f) * (1.0f / 16777216.0f);
      u[4] = ((float)(unsigned)(h2 >> 40) + 0.5f) * (1.0f / 16777216.0f);
      u[5] = ((float)((unsigned)(h2 >> 16) & 0xFFFFFFu) + 0.5f) * (1.0f / 16777216.0f);
      u[6] = ((float)(unsigned)(h3 >> 40) + 0.5f) * (1.0f / 16777216.0f);
      u[7] = ((float)((unsigned)(h3 >> 16) & 0xFFFFFFu) + 0.5f) * (1.0f / 16777216.0f);
      float4 z0 = *(const float4*)(zrow + tm0);
      float4 z1 = *(const float4*)(zrow + tm0 + 4);
      const float* zvp0 = &z0.x;
      const float* zvp1 = &z1.x;
      #pragma unroll
      for (int j = 0; j < 8; ++j) {
        float uu = fminf(fmaxf(u[j], 1e-6f), 1.0f - 1e-6f);
        float e = ems[tm0 + j];
        float den = fmaf(e, 1.0f - uu, uu);
        float adj = uu * __builtin_amdgcn_rcpf(den);
        float zv = (j < 4) ? zvp0[j] : zvp1[j - 4];
        a[ks][j] = f2bf(adj * zv);
      }
    }

    f32x4 acc[4] = {};
    #pragma unroll
    for (int nt = 0; nt < 4; ++nt) {
      const short* Brow = Bls + (nt * 16 + lrow) * 328 + g * 8;
      #pragma unroll
      for (int ks = 0; ks < 10; ++ks) {
        bf16x8 bv = *(const bf16x8*)(Brow + ks * 32);
        acc[nt] = __builtin_amdgcn_mfma_f32_16x16x32_bf16(a[ks], bv, acc[nt], 0, 0, 0);
      }
    }

    float b0v[4], w1v[4];
    #pragma unroll
    for (int nt = 0; nt < 4; ++nt) {
      int h = nt * 16 + lrow;
      b0v[nt] = tb0[m * NH + h];
      w1v[nt] = tW1[m * NH + h];
    }

    const int d = m >> 4;
    const float lv_t = t_logvar[m];
    const float lv_e = lve[d];
    const float inv2var = 0.5f * expf(-lv_t);
    const float qvar = expf(lv_e);
    const float cterm = 0.5f * lv_t - 0.5f * lv_e - 0.5f;
    const float bv1 = tb1[m];

    float klw = 0.0f;
    #pragma unroll
    for (int reg = 0; reg < 4; ++reg) {
      float v = 0.0f;
      #pragma unroll
      for (int nt = 0; nt < 4; ++nt) {
        float hv = acc[nt][reg] + b0v[nt];
        hv = fmaxf(hv, 0.01f * hv);
        v += hv * w1v[nt];
      }
      #pragma unroll
      for (int off = 1; off < 16; off <<= 1) v += __shfl_xor(v, off, 16);
      if (lrow == 0) {
        int b = b0 + w * 16 + g * 4 + reg;
        float pz = v + bv1;
        float diff = mu_t[(size_t)b * NM + m] - pz;
        klw += cterm + (qvar + diff * diff) * inv2var;
      }
    }
    klw += __shfl_xor(klw, 16, 64);
    klw += __shfl_xor(klw, 32, 64);

    if (l == 0) redb[w] = klw;
    __syncthreads();
    if (tid == 0) {
      float s = 0.f;
      #pragma unroll
      for (int i = 0; i < 8; ++i) s += redb[i];
      kl_partial[(bid & 3) * NM + m] = s;
    }
  } else {
    // ---------------- decoder + recon ----------------
    const int idx = bid - 320;
    const int d = idx >> 8, xx = idx & 255;
    const int w8 = tid >> 6, l = tid & 63;
    const int mb = w8 >> 2, w = w8 & 3;
    const int lrow = l & 15, g = l >> 4;

    bf16x8 bfr[4];
    const short* Bbase = QtD + ((size_t)((d * NDX + xx) * NH)) * 32;
    #pragma unroll
    for (int nt = 0; nt < 4; ++nt)
      bfr[nt] = *(const bf16x8*)(Bbase + (nt * 16 + lrow) * 32 + g * 8);

    f32x4 acc[4][4] = {};
    #pragma unroll
    for (int mt = 0; mt < 4; ++mt) {
      int b = mb * 256 + w * 64 + mt * 16 + lrow;
      bf16x8 a = {0, 0, 0, 0, 0, 0, 0, 0};
      if (g < 2) {
        const float* zp = zt + (size_t)b * NM + d * NDZ + g * 8;
        float4 f0 = *(const float4*)zp;
        float4 f1 = *(const float4*)(zp + 4);
        a[0] = f2bf(f0.x); a[1] = f2bf(f0.y); a[2] = f2bf(f0.z); a[3] = f2bf(f0.w);
        a[4] = f2bf(f1.x); a[5] = f2bf(f1.y); a[6] = f2bf(f1.z); a[7] = f2bf(f1.w);
      }
      #pragma unroll
      for (int nt = 0; nt < 4; ++nt)
        acc[mt][nt] = __builtin_amdgcn_mfma_f32_16x16x32_bf16(a, bfr[nt], acc[mt][nt], 0, 0, 0);
    }

    float db0v[4], dW1v[4];
    #pragma unroll
    for (int nt = 0; nt < 4; ++nt) {
      int h = nt * 16 + lrow;
      db0v[nt] = db0[xx * NH + h];
      dW1v[nt] = dW1[xx * NH + h];
    }
    const float lv = lvd[d];
    const float inv_std = expf(-0.5f * lv);
    const float cterm = -0.5f * lv - 0.5f * LOG2PI_F;
    const float b1v = db1[xx];

    float racc = 0.0f;
    #pragma unroll
    for (int mt = 0; mt < 4; ++mt) {
      float rs[4];
      #pragma unroll
      for (int reg = 0; reg < 4; ++reg) {
        float v = 0.0f;
        #pragma unroll
        for (int nt = 0; nt < 4; ++nt) {
          float hv = acc[mt][nt][reg] + db0v[nt];
          hv = fmaxf(hv, 0.01f * hv);
          v += hv * dW1v[nt];
        }
        #pragma unroll
        for (int off = 1; off < 16; off <<= 1) v += __shfl_xor(v, off, 16);
        rs[reg] = v;
      }
      if (lrow == 0) {
        int b = mb * 256 + w * 64 + mt * 16 + g * 4;
        float4 yv = *(const float4*)&yT[((size_t)d * NDX + xx) * NB + b];
        const float* yvp = &yv.x;
        #pragma unroll
        for (int reg = 0; reg < 4; ++reg) {
          float px = rs[reg] + b1v;
          float e = (yvp[reg] - px) * inv_std;
          racc += -0.5f * e * e + cterm;
        }
      }
    }
    racc += __shfl_xor(racc, 16, 64);
    racc += __shfl_xor(racc, 32, 64);

    if (l == 0) redb[w8] = racc;
    __syncthreads();
    if (tid == 0) {
      float s = 0.f;
      #pragma unroll
      for (int i = 0; i < 8; ++i) s += redb[i];
      rec_partial[(size_t)d * NDX + xx] = s;
    }
  }
}

// =====================================================================
// K3: final reduction -> loss = (sum_kl - sum_recon) / B
// =====================================================================
__global__ __launch_bounds__(256) void k_reduce(
    const float* __restrict__ rp, const float* __restrict__ kp,
    float* __restrict__ out)
{
  __shared__ float sr[4], sk[4];
  float r = 0.f, k = 0.f;
  for (int i = threadIdx.x; i < 1280; i += 256) r += rp[i];
  for (int i = threadIdx.x; i < 320; i += 256) k += kp[i];
  #pragma unroll
  for (int off = 32; off; off >>= 1) {
    r += __shfl_xor(r, off, 64);
    k += __shfl_xor(k, off, 64);
  }
  int wv = threadIdx.x >> 6;
  if ((threadIdx.x & 63) == 0) { sr[wv] = r; sk[wv] = k; }
  __syncthreads();
  if (threadIdx.x == 0) {
    float R = sr[0] + sr[1] + sr[2] + sr[3];
    float K = sk[0] + sk[1] + sk[2] + sk[3];
    out[0] = (K - R) / (float)NB;
  }
}

// =====================================================================
extern "C" void kernel_launch(void* const* d_in, const int* in_sizes, int n_in,
                              void* d_out, int out_size, void* d_ws, size_t ws_size,
                              hipStream_t stream) {
  (void)in_sizes; (void)n_in; (void)out_size; (void)ws_size;
  const float* x        = (const float*)d_in[0];
  const float* y        = (const float*)d_in[1];
  const float* mask_p   = (const float*)d_in[2];
  const float* w_enc    = (const float*)d_in[3];
  const float* w_dec    = (const float*)d_in[4];
  const float* enc_W0   = (const float*)d_in[5];
  const float* enc_b0   = (const float*)d_in[6];
  const float* enc_W1   = (const float*)d_in[7];
  const float* enc_b1   = (const float*)d_in[8];
  const float* dec_W0   = (const float*)d_in[9];
  const float* dec_b0   = (const float*)d_in[10];
  const float* dec_W1   = (const float*)d_in[11];
  const float* dec_b1   = (const float*)d_in[12];
  const float* t_W0     = (const float*)d_in[13];
  const float* t_b0     = (const float*)d_in[14];
  const float* t_W1     = (const float*)d_in[15];
  const float* t_b1     = (const float*)d_in[16];
  const float* lv_enc   = (const float*)d_in[17];
  const float* lv_dec   = (const float*)d_in[18];
  const float* t_logvar = (const float*)d_in[19];

  float* ws     = (float*)d_ws;
  float* z_past = ws;                         // 163840 f32
  float* mu_t   = z_past + 163840;            // 40960
  float* z_t    = mu_t + 40960;               // 40960
  float* rec_p  = z_t + 40960;                // 1280
  float* kl_p   = rec_p + 1280;               // 320
  float* yTb    = kl_p + 320;                 // 655360
  short* QtD    = (short*)(yTb + 655360);     // 5*256*64*32
  short* TtB    = QtD + 5 * NDX * NH * 32;    // 80*64*320

  k_enc_mfma<<<1280, 512, 0, stream>>>(
      x, y, w_enc, enc_W0, enc_b0, enc_W1, enc_b1, lv_enc,
      z_past, mu_t, z_t, w_dec, dec_W0, QtD, t_W0, TtB, yTb);
  k_tail<<<1600, 512, 0, stream>>>(
      mask_p, z_past, TtB, t_b0, t_W1, t_b1, lv_enc, t_logvar, mu_t, kl_p,
      z_t, QtD, yTb, dec_b0, dec_W1, dec_b1, lv_dec, rec_p);
  k_reduce<<<1, 256, 0, stream>>>(rec_p, kl_p, (float*)d_out);
}

// Round 11
// 66.632 us; speedup vs baseline: 1.2818x; 1.2818x over previous
//
#include <hip/hip_runtime.h>
#include <cstdint>

// ---- problem dims ----
constexpr int NB = 512, NTAU = 4, ND = 5, NDX = 256, NDZ = 16, NH = 64;
constexpr int NM  = ND * NDZ;          // 80
constexpr int NTM = NTAU * NM;         // 320
constexpr int NSAMP = NB * NTAU + NB;  // 2560 (past samples then t samples)
constexpr float LOG2PI_F = 1.8378770664093453f;

typedef __attribute__((ext_vector_type(8))) short bf16x8;
typedef __attribute__((ext_vector_type(4))) float f32x4;

// ---- counter-based RNG (distribution-exact stand-in for jax.random) ----
__device__ __forceinline__ unsigned long long mix64(unsigned long long z) {
  z += 0x9E3779B97F4A7C15ull;
  z = (z ^ (z >> 30)) * 0xBF58476D1CE4E5B9ull;
  z = (z ^ (z >> 27)) * 0x94D049BB133111EBull;
  return z ^ (z >> 31);
}
__device__ __forceinline__ float u01f(unsigned long long h) {
  return ((float)(unsigned)(h >> 40) + 0.5f) * (1.0f / 16777216.0f);
}
__device__ __forceinline__ float rng_normal(unsigned long long salt, unsigned long long idx) {
  float u1 = u01f(mix64(salt + 2ull * idx));
  float u2 = u01f(mix64(salt + 2ull * idx + 1ull));
  float r = sqrtf(-2.0f * logf(u1));
  return r * cosf(6.283185307179586f * u2);
}
constexpr unsigned long long SALT_ADJ = 0x1000000000000ull;
constexpr unsigned long long SALT_EP  = 0x2000000000000ull;
constexpr unsigned long long SALT_ET  = 0x3000000000000ull;

__device__ __forceinline__ short f2bf(float f) {
  unsigned u = __float_as_uint(f);
  unsigned r = (u + 0x7FFFu + ((u >> 16) & 1u)) >> 16;
  return (short)r;
}

// =====================================================================
// K0: PtE[d][col=z*64+h][k] = bf16(w_enc[d,z,k] * eW0[z,k,h])
// via LDS transpose; all global reads/writes coalesced.
// grid 320: d = bid/64, z = (bid%64)>>2, kb = bid&3. block 256.
// =====================================================================
__global__ __launch_bounds__(256) void k_prepP(
    const float* __restrict__ w_enc, const float* __restrict__ eW0,
    short* __restrict__ PtE)
{
  __shared__ float lds[64][65];
  const int bid = blockIdx.x;
  const int d  = bid >> 6;
  const int z  = (bid & 63) >> 2;
  const int k0 = (bid & 3) * 64;
  const int tid = threadIdx.x;

  // load eW0[z][k0+kk][h]: consecutive tid -> consecutive h (coalesced)
  for (int i = tid; i < 64 * 64; i += 256) {
    int kk = i >> 6, h = i & 63;
    lds[kk][h] = eW0[((size_t)z * NDX + k0 + kk) * NH + h];
  }
  __syncthreads();
  // write PtE[d][z*64+h][k0+kk]: consecutive tid -> consecutive kk (coalesced)
  for (int i = tid; i < 64 * 64; i += 256) {
    int h = i >> 6, kk = i & 63;
    float v = w_enc[((size_t)d * NDZ + z) * NDX + k0 + kk] * lds[kk][h];
    PtE[((size_t)(d * 1024 + z * 64 + h)) * NDX + k0 + kk] = f2bf(v);
  }
}

// =====================================================================
// K1: encoder GEMM (PtE-staged B, round-9 structure) + fused reparam,
//     plus independent prep block-ranges consumed only by K2:
// [0,400)    enc: d=bid/80, zq=(bid%80)/20, sb=bid%20
// [400,560)  QtD prep
// [560,960)  TtB prep
// [960,1280) yT prep
// =====================================================================
__global__ __launch_bounds__(512) void k_enc_mfma(
    const float* __restrict__ x, const float* __restrict__ y,
    const short* __restrict__ PtE,
    const float* __restrict__ b0, const float* __restrict__ W1,
    const float* __restrict__ b1, const float* __restrict__ lve,
    float* __restrict__ z_past, float* __restrict__ mu_t, float* __restrict__ z_t,
    const float* __restrict__ w_dec, const float* __restrict__ dW0,
    short* __restrict__ QtD,
    const float* __restrict__ tW0, short* __restrict__ TtB,
    float* __restrict__ yT)
{
  __shared__ __align__(16) char smem[35840];
  const int bid = blockIdx.x;
  const int tid = threadIdx.x;

  if (bid < 400) {
    short* Bs = (short*)smem;                        // 64*264 shorts = 33792 B
    float (*mu_s)[4] = (float(*)[4])(smem + 33792);  // [128][4] = 2048 B

    const int d = bid / 80;
    const int r80 = bid % 80;
    const int zq = r80 / 20;
    const int s0 = (r80 % 20) * 128;
    const int w = tid >> 6, l = tid & 63;
    const int lrow = l & 15, g = l >> 4;

    // A fragments: f32 direct read + inline f2bf (bit-identical to bf16 path)
    const int srow = s0 + w * 16 + lrow;
    const float* Asrc = (srow < NB * NTAU)
        ? &x[((size_t)srow * ND + d) * NDX]
        : &y[((size_t)(srow - NB * NTAU) * ND + d) * NDX];
    bf16x8 a[8];
    #pragma unroll
    for (int ks = 0; ks < 8; ++ks) {
      const float* p = Asrc + g * 8 + ks * 32;
      float4 f0 = *(const float4*)p;
      float4 f1 = *(const float4*)(p + 4);
      a[ks][0] = f2bf(f0.x); a[ks][1] = f2bf(f0.y);
      a[ks][2] = f2bf(f0.z); a[ks][3] = f2bf(f0.w);
      a[ks][4] = f2bf(f1.x); a[ks][5] = f2bf(f1.y);
      a[ks][6] = f2bf(f1.z); a[ks][7] = f2bf(f1.w);
    }

    const int stg_row = tid >> 3;        // 0..63
    const int stg_c   = (tid & 7) * 32;  // 32-short chunk

    for (int zi = 0; zi < 4; ++zi) {
      const int z = zq * 4 + zi;
      {
        const short* src = PtE + ((size_t)(d * 1024 + z * 64 + stg_row)) * NDX + stg_c;
        short* dst = Bs + stg_row * 264 + stg_c;
        #pragma unroll
        for (int j = 0; j < 4; ++j)
          *(bf16x8*)(dst + j * 8) = *(const bf16x8*)(src + j * 8);
      }
      __syncthreads();

      f32x4 acc[4] = {};
      #pragma unroll
      for (int nt = 0; nt < 4; ++nt) {
        const short* Brow = Bs + (nt * 16 + lrow) * 264 + g * 8;
        #pragma unroll
        for (int ks = 0; ks < 8; ++ks) {
          bf16x8 bv = *(const bf16x8*)(Brow + ks * 32);
          acc[nt] = __builtin_amdgcn_mfma_f32_16x16x32_bf16(a[ks], bv, acc[nt], 0, 0, 0);
        }
      }

      float b0v[4], w1v[4];
      #pragma unroll
      for (int nt = 0; nt < 4; ++nt) {
        int h = nt * 16 + lrow;
        b0v[nt] = b0[z * NH + h];
        w1v[nt] = W1[z * NH + h];
      }
      const float b1v = b1[z];
      #pragma unroll
      for (int reg = 0; reg < 4; ++reg) {
        float v = 0.0f;
        #pragma unroll
        for (int nt = 0; nt < 4; ++nt) {
          float hv = acc[nt][reg] + b0v[nt];
          hv = fmaxf(hv, 0.01f * hv);
          v += hv * w1v[nt];
        }
        #pragma unroll
        for (int off = 1; off < 16; off <<= 1) v += __shfl_xor(v, off, 16);
        if (lrow == 0)
          mu_s[w * 16 + g * 4 + reg][zi] = v + b1v;
      }
      __syncthreads();
    }

    // fused reparameterization: 512 threads x 1 element (sl, zi)
    {
      const int sl = tid >> 2, zi = tid & 3;
      const int z = zq * 4 + zi;
      const int s = s0 + sl;
      const int m = d * NDZ + z;
      float mu = mu_s[sl][zi];
      float qs = expf(0.5f * lve[d]);
      if (s < NB * NTAU) {
        float eps = rng_normal(SALT_EP, (unsigned long long)s * NM + m);
        z_past[(size_t)s * NM + m] = mu + qs * eps;
      } else {
        int b = s - NB * NTAU;
        float eps = rng_normal(SALT_ET, (unsigned long long)b * NM + m);
        size_t o = (size_t)b * NM + m;
        mu_t[o] = mu;
        z_t[o]  = mu + qs * eps;
      }
    }
  } else if (bid < 560) {
    // QtD[((d*256+xx)*64+h)][k<32] = bf16(w_dec[d,xx,z]*dW0[xx,z,h]), 0-pad
    int t = (bid - 400) * 512 + tid;     // < 81920
    int d = t / (NDX * NH);
    int r = t % (NDX * NH);
    int xx = r >> 6, h = r & 63;
    size_t base = (size_t)t * 32;
    #pragma unroll
    for (int z = 0; z < NDZ; ++z)
      QtD[base + z] = f2bf(w_dec[((size_t)d * NDX + xx) * NDZ + z] *
                           dW0[((size_t)xx * NDZ + z) * NH + h]);
    #pragma unroll
    for (int z = NDZ; z < 32; ++z) QtD[base + z] = 0;
  } else if (bid < 960) {
    // TtB[m][h][k] = bf16(tW0[m][k][h]) via LDS transpose
    short (*lds)[65] = (short(*)[65])smem;
    int r = bid - 560;
    int kt = r % 5, m = r / 5;
    int k0 = kt * 64;
    for (int idx = tid; idx < 64 * 64; idx += 512) {
      int hh = idx & 63, kk = idx >> 6;
      lds[kk][hh] = f2bf(tW0[((size_t)m * NTM + k0 + kk) * NH + hh]);
    }
    __syncthreads();
    for (int idx = tid; idx < 64 * 64; idx += 512) {
      int kk = idx & 63, hh = idx >> 6;
      TtB[((size_t)m * NH + hh) * NTM + k0 + kk] = lds[kk][hh];
    }
  } else {
    // yT[d][xx][b] = y[b][d][xx], 4 b's per thread
    int e0 = ((bid - 960) * 512 + tid) * 4;   // < 655360
    int d = e0 / (NDX * NB);
    int rem = e0 % (NDX * NB);
    int xx = rem >> 9, b0i = rem & 511;
    float4 o;
    o.x = y[((size_t)(b0i + 0) * ND + d) * NDX + xx];
    o.y = y[((size_t)(b0i + 1) * ND + d) * NDX + xx];
    o.z = y[((size_t)(b0i + 2) * ND + d) * NDX + xx];
    o.w = y[((size_t)(b0i + 3) * ND + d) * NDX + xx];
    *(float4*)&yT[e0] = o;
  }
}

// =====================================================================
// K2: blocks [0,320) = transition GEMM + KL (register-direct gating,
//     inline em=expf(-mask)); blocks [320,1600) = decoder + recon.
// =====================================================================
__global__ __launch_bounds__(512) void k_tail(
    const float* __restrict__ mask_param, const float* __restrict__ z_past,
    const short* __restrict__ TtB,
    const float* __restrict__ tb0, const float* __restrict__ tW1,
    const float* __restrict__ tb1, const float* __restrict__ lve,
    const float* __restrict__ t_logvar, const float* __restrict__ mu_t,
    float* __restrict__ kl_partial,
    const float* __restrict__ zt, const short* __restrict__ QtD,
    const float* __restrict__ yT, const float* __restrict__ db0,
    const float* __restrict__ dW1, const float* __restrict__ db1,
    const float* __restrict__ lvd, float* __restrict__ rec_partial)
{
  __shared__ __align__(16) short Bls[64 * 328];
  __shared__ float ems[NTM];
  __shared__ float redb[8];

  const int bid = blockIdx.x;
  const int tid = threadIdx.x;

  if (bid < 320) {
    // ---------------- transition + KL ----------------
    const int m = bid >> 2;
    const int b0 = (bid & 3) * 128;
    const int w = tid >> 6, l = tid & 63;
    const int lrow = l & 15, g = l >> 4;

    for (int i = tid; i < NTM; i += 512) {
      int t = i / NM, s = i - t * NM;
      ems[i] = expf(-mask_param[(t * NM + m) * NM + s]);
    }
    {
      const int r = tid >> 3;
      const int c0 = (tid & 7) * 40;
      const short* src = TtB + ((size_t)(m * NH + r)) * NTM + c0;
      short* dst = Bls + r * 328 + c0;
      #pragma unroll
      for (int j = 0; j < 5; ++j)
        *(bf16x8*)(dst + j * 8) = *(const bf16x8*)(src + j * 8);
    }
    __syncthreads();

    const int brow = b0 + w * 16 + lrow;
    const float* zrow = z_past + (size_t)brow * NTM;
    bf16x8 a[10];
    #pragma unroll
    for (int ks = 0; ks < 10; ++ks) {
      const int tm0 = g * 8 + ks * 32;
      const int t = tm0 / NM;
      const int s0 = tm0 - t * NM;
      unsigned long long aibase =
          ((unsigned long long)((brow * NTAU + t) * NM + m)) * NM + s0;
      unsigned long long h0 = mix64(SALT_ADJ + aibase);
      unsigned long long h1 = mix64(SALT_ADJ + aibase + 2);
      unsigned long long h2 = mix64(SALT_ADJ + aibase + 4);
      unsigned long long h3 = mix64(SALT_ADJ + aibase + 6);
      float u[8];
      u[0] = ((float)(unsigned)(h0 >> 40) + 0.5f) * (1.0f / 16777216.0f);
      u[1] = ((float)((unsigned)(h0 >> 16) & 0xFFFFFFu) + 0.5f) * (1.0f / 16777216.0f);
      u[2] = ((float)(unsigned)(h1 >> 40) + 0.5f) * (1.0f / 16777216.0f);
      u[3] = ((float)((unsigned)(h1 >> 16) & 0xFFFFFFu) + 0.5f) * (1.0f / 16777216.0f);
      u[4] = ((float)(unsigned)(h2 >> 40) + 0.5f) * (1.0f / 16777216.0f);
      u[5] = ((float)((unsigned)(h2 >> 16) & 0xFFFFFFu) + 0.5f) * (1.0f / 16777216.0f);
      u[6] = ((float)(unsigned)(h3 >> 40) + 0.5f) * (1.0f / 16777216.0f);
      u[7] = ((float)((unsigned)(h3 >> 16) & 0xFFFFFFu) + 0.5f) * (1.0f / 16777216.0f);
      float4 z0 = *(const float4*)(zrow + tm0);
      float4 z1 = *(const float4*)(zrow + tm0 + 4);
      const float* zvp0 = &z0.x;
      const float* zvp1 = &z1.x;
      #pragma unroll
      for (int j = 0; j < 8; ++j) {
        float uu = fminf(fmaxf(u[j], 1e-6f), 1.0f - 1e-6f);
        float e = ems[tm0 + j];
        float den = fmaf(e, 1.0f - uu, uu);
        float adj = uu * __builtin_amdgcn_rcpf(den);
        float zv = (j < 4) ? zvp0[j] : zvp1[j - 4];
        a[ks][j] = f2bf(adj * zv);
      }
    }

    f32x4 acc[4] = {};
    #pragma unroll
    for (int nt = 0; nt < 4; ++nt) {
      const short* Brow = Bls + (nt * 16 + lrow) * 328 + g * 8;
      #pragma unroll
      for (int ks = 0; ks < 10; ++ks) {
        bf16x8 bv = *(const bf16x8*)(Brow + ks * 32);
        acc[nt] = __builtin_amdgcn_mfma_f32_16x16x32_bf16(a[ks], bv, acc[nt], 0, 0, 0);
      }
    }

    float b0v[4], w1v[4];
    #pragma unroll
    for (int nt = 0; nt < 4; ++nt) {
      int h = nt * 16 + lrow;
      b0v[nt] = tb0[m * NH + h];
      w1v[nt] = tW1[m * NH + h];
    }

    const int d = m >> 4;
    const float lv_t = t_logvar[m];
    const float lv_e = lve[d];
    const float inv2var = 0.5f * expf(-lv_t);
    const float qvar = expf(lv_e);
    const float cterm = 0.5f * lv_t - 0.5f * lv_e - 0.5f;
    const float bv1 = tb1[m];

    float klw = 0.0f;
    #pragma unroll
    for (int reg = 0; reg < 4; ++reg) {
      float v = 0.0f;
      #pragma unroll
      for (int nt = 0; nt < 4; ++nt) {
        float hv = acc[nt][reg] + b0v[nt];
        hv = fmaxf(hv, 0.01f * hv);
        v += hv * w1v[nt];
      }
      #pragma unroll
      for (int off = 1; off < 16; off <<= 1) v += __shfl_xor(v, off, 16);
      if (lrow == 0) {
        int b = b0 + w * 16 + g * 4 + reg;
        float pz = v + bv1;
        float diff = mu_t[(size_t)b * NM + m] - pz;
        klw += cterm + (qvar + diff * diff) * inv2var;
      }
    }
    klw += __shfl_xor(klw, 16, 64);
    klw += __shfl_xor(klw, 32, 64);

    if (l == 0) redb[w] = klw;
    __syncthreads();
    if (tid == 0) {
      float s = 0.f;
      #pragma unroll
      for (int i = 0; i < 8; ++i) s += redb[i];
      kl_partial[(bid & 3) * NM + m] = s;
    }
  } else {
    // ---------------- decoder + recon ----------------
    const int idx = bid - 320;
    const int d = idx >> 8, xx = idx & 255;
    const int w8 = tid >> 6, l = tid & 63;
    const int mb = w8 >> 2, w = w8 & 3;
    const int lrow = l & 15, g = l >> 4;

    bf16x8 bfr[4];
    const short* Bbase = QtD + ((size_t)((d * NDX + xx) * NH)) * 32;
    #pragma unroll
    for (int nt = 0; nt < 4; ++nt)
      bfr[nt] = *(const bf16x8*)(Bbase + (nt * 16 + lrow) * 32 + g * 8);

    f32x4 acc[4][4] = {};
    #pragma unroll
    for (int mt = 0; mt < 4; ++mt) {
      int b = mb * 256 + w * 64 + mt * 16 + lrow;
      bf16x8 a = {0, 0, 0, 0, 0, 0, 0, 0};
      if (g < 2) {
        const float* zp = zt + (size_t)b * NM + d * NDZ + g * 8;
        float4 f0 = *(const float4*)zp;
        float4 f1 = *(const float4*)(zp + 4);
        a[0] = f2bf(f0.x); a[1] = f2bf(f0.y); a[2] = f2bf(f0.z); a[3] = f2bf(f0.w);
        a[4] = f2bf(f1.x); a[5] = f2bf(f1.y); a[6] = f2bf(f1.z); a[7] = f2bf(f1.w);
      }
      #pragma unroll
      for (int nt = 0; nt < 4; ++nt)
        acc[mt][nt] = __builtin_amdgcn_mfma_f32_16x16x32_bf16(a, bfr[nt], acc[mt][nt], 0, 0, 0);
    }

    float db0v[4], dW1v[4];
    #pragma unroll
    for (int nt = 0; nt < 4; ++nt) {
      int h = nt * 16 + lrow;
      db0v[nt] = db0[xx * NH + h];
      dW1v[nt] = dW1[xx * NH + h];
    }
    const float lv = lvd[d];
    const float inv_std = expf(-0.5f * lv);
    const float cterm = -0.5f * lv - 0.5f * LOG2PI_F;
    const float b1v = db1[xx];

    float racc = 0.0f;
    #pragma unroll
    for (int mt = 0; mt < 4; ++mt) {
      float rs[4];
      #pragma unroll
      for (int reg = 0; reg < 4; ++reg) {
        float v = 0.0f;
        #pragma unroll
        for (int nt = 0; nt < 4; ++nt) {
          float hv = acc[mt][nt][reg] + db0v[nt];
          hv = fmaxf(hv, 0.01f * hv);
          v += hv * dW1v[nt];
        }
        #pragma unroll
        for (int off = 1; off < 16; off <<= 1) v += __shfl_xor(v, off, 16);
        rs[reg] = v;
      }
      if (lrow == 0) {
        int b = mb * 256 + w * 64 + mt * 16 + g * 4;
        float4 yv = *(const float4*)&yT[((size_t)d * NDX + xx) * NB + b];
        const float* yvp = &yv.x;
        #pragma unroll
        for (int reg = 0; reg < 4; ++reg) {
          float px = rs[reg] + b1v;
          float e = (yvp[reg] - px) * inv_std;
          racc += -0.5f * e * e + cterm;
        }
      }
    }
    racc += __shfl_xor(racc, 16, 64);
    racc += __shfl_xor(racc, 32, 64);

    if (l == 0) redb[w8] = racc;
    __syncthreads();
    if (tid == 0) {
      float s = 0.f;
      #pragma unroll
      for (int i = 0; i < 8; ++i) s += redb[i];
      rec_partial[(size_t)d * NDX + xx] = s;
    }
  }
}

// =====================================================================
// K3: final reduction -> loss = (sum_kl - sum_recon) / B
// =====================================================================
__global__ __launch_bounds__(256) void k_reduce(
    const float* __restrict__ rp, const float* __restrict__ kp,
    float* __restrict__ out)
{
  __shared__ float sr[4], sk[4];
  float r = 0.f, k = 0.f;
  for (int i = threadIdx.x; i < 1280; i += 256) r += rp[i];
  for (int i = threadIdx.x; i < 320; i += 256) k += kp[i];
  #pragma unroll
  for (int off = 32; off; off >>= 1) {
    r += __shfl_xor(r, off, 64);
    k += __shfl_xor(k, off, 64);
  }
  int wv = threadIdx.x >> 6;
  if ((threadIdx.x & 63) == 0) { sr[wv] = r; sk[wv] = k; }
  __syncthreads();
  if (threadIdx.x == 0) {
    float R = sr[0] + sr[1] + sr[2] + sr[3];
    float K = sk[0] + sk[1] + sk[2] + sk[3];
    out[0] = (K - R) / (float)NB;
  }
}

// =====================================================================
extern "C" void kernel_launch(void* const* d_in, const int* in_sizes, int n_in,
                              void* d_out, int out_size, void* d_ws, size_t ws_size,
                              hipStream_t stream) {
  (void)in_sizes; (void)n_in; (void)out_size; (void)ws_size;
  const float* x        = (const float*)d_in[0];
  const float* y        = (const float*)d_in[1];
  const float* mask_p   = (const float*)d_in[2];
  const float* w_enc    = (const float*)d_in[3];
  const float* w_dec    = (const float*)d_in[4];
  const float* enc_W0   = (const float*)d_in[5];
  const float* enc_b0   = (const float*)d_in[6];
  const float* enc_W1   = (const float*)d_in[7];
  const float* enc_b1   = (const float*)d_in[8];
  const float* dec_W0   = (const float*)d_in[9];
  const float* dec_b0   = (const float*)d_in[10];
  const float* dec_W1   = (const float*)d_in[11];
  const float* dec_b1   = (const float*)d_in[12];
  const float* t_W0     = (const float*)d_in[13];
  const float* t_b0     = (const float*)d_in[14];
  const float* t_W1     = (const float*)d_in[15];
  const float* t_b1     = (const float*)d_in[16];
  const float* lv_enc   = (const float*)d_in[17];
  const float* lv_dec   = (const float*)d_in[18];
  const float* t_logvar = (const float*)d_in[19];

  float* ws     = (float*)d_ws;
  float* z_past = ws;                         // 163840 f32
  float* mu_t   = z_past + 163840;            // 40960
  float* z_t    = mu_t + 40960;               // 40960
  float* rec_p  = z_t + 40960;                // 1280
  float* kl_p   = rec_p + 1280;               // 320
  float* yTb    = kl_p + 320;                 // 655360
  short* PtE    = (short*)(yTb + 655360);     // 5*1024*256
  short* QtD    = PtE + 5 * 1024 * NDX;       // 5*256*64*32
  short* TtB    = QtD + 5 * NDX * NH * 32;    // 80*64*320

  k_prepP<<<320, 256, 0, stream>>>(w_enc, enc_W0, PtE);
  k_enc_mfma<<<1280, 512, 0, stream>>>(
      x, y, PtE, enc_b0, enc_W1, enc_b1, lv_enc,
      z_past, mu_t, z_t, w_dec, dec_W0, QtD, t_W0, TtB, yTb);
  k_tail<<<1600, 512, 0, stream>>>(
      mask_p, z_past, TtB, t_b0, t_W1, t_b1, lv_enc, t_logvar, mu_t, kl_p,
      z_t, QtD, yTb, dec_b0, dec_W1, dec_b1, lv_dec, rec_p);
  k_reduce<<<1, 256, 0, stream>>>(rec_p, kl_p, (float*)d_out);
}